// Round 5
// baseline (420.126 us; speedup 1.0000x reference)
//
#include <hip/hip_runtime.h>
#include <math.h>

#define CIN  256
#define COUT 128
#define HW   4096
#define NB   4
#define OCSPLIT 4
#define CSPLIT  4
#define CPC  (CIN / CSPLIT)   // 64 channels per k_dcn block

// ---------------- weight prep:
// w_s[((c*4 + wv)*32 + co')*9 + k] = w_dcn[wv*32+co'][c][k] * bn_scale
__global__ __launch_bounds__(256) void k_prep_w(
    const float* __restrict__ w_dcn, const float* __restrict__ b_dcn,
    const float* __restrict__ gamma, const float* __restrict__ beta,
    const float* __restrict__ rmean, const float* __restrict__ rvar,
    float* __restrict__ w_s, float* __restrict__ bias_t)
{
  int t = blockIdx.x * 256 + threadIdx.x;
  if (t < COUT) {
    float sc = gamma[t] * rsqrtf(rvar[t] + 1e-5f);
    bias_t[t] = b_dcn[t] * sc + beta[t] - rmean[t] * sc;
  }
  if (t >= CIN * COUT * 9) return;
  int k = t % 9;
  int q = t / 9;
  int co = q % COUT;
  int c  = q / COUT;
  float sc = gamma[co] * rsqrtf(rvar[co] + 1e-5f);
  w_s[((size_t)(c * 4 + (co >> 5)) * 32 + (co & 31)) * 9 + k] =
      w_dcn[((size_t)co * CIN + c) * 9 + k] * sc;
}

// ---------------- offset conv (27 ch, 3x3, pad 1), split over ci into OCSPLIT partials
__global__ __launch_bounds__(256) void k_off_conv(
    const float* __restrict__ x, const float* __restrict__ w_off,
    float* __restrict__ om_part)
{
  int blk = blockIdx.x;
  int split = blk & (OCSPLIT - 1);
  int bh = blk / OCSPLIT;
  int b = bh >> 6, h = bh & 63;
  int ci0 = split * (CIN / OCSPLIT);

  __shared__ float xs[8][3][66];
  __shared__ float wl[8][27][9];

  int t = threadIdx.x;
  int w = t & 63;
  int slot = t >> 6;

  float acc[7];
#pragma unroll
  for (int j = 0; j < 7; ++j) acc[j] = 0.f;

  const int NT = (CIN / OCSPLIT) / 8;
  for (int tile = 0; tile < NT; ++tile) {
    int cb = ci0 + tile * 8;
    __syncthreads();
    for (int j = t; j < 8 * 3 * 66; j += 256) {
      int ci = j / 198, rem = j - ci * 198;
      int r = rem / 66, wp = rem - r * 66;
      int hh = h + r - 1, ww = wp - 1;
      float v = 0.f;
      if (hh >= 0 && hh < 64 && (unsigned)ww < 64u)
        v = x[(((size_t)b * CIN + cb + ci) * 64 + hh) * 64 + ww];
      xs[ci][r][wp] = v;
    }
    for (int j = t; j < 8 * 27 * 9; j += 256) {
      int ci = j / 243, rem = j - ci * 243;
      int c2 = rem / 9, k = rem - c2 * 9;
      wl[ci][c2][k] = w_off[((size_t)c2 * CIN + cb + ci) * 9 + k];
    }
    __syncthreads();
#pragma unroll 1
    for (int ci = 0; ci < 8; ++ci) {
      float xv[3][3];
#pragma unroll
      for (int r = 0; r < 3; ++r)
#pragma unroll
        for (int d = 0; d < 3; ++d)
          xv[r][d] = xs[ci][r][w + d];
#pragma unroll
      for (int j = 0; j < 7; ++j) {
        int co = slot + 4 * j;
        if (co < 27) {
#pragma unroll
          for (int r = 0; r < 3; ++r)
#pragma unroll
            for (int d = 0; d < 3; ++d)
              acc[j] = fmaf(wl[ci][co][r * 3 + d], xv[r][d], acc[j]);
        }
      }
    }
  }
#pragma unroll
  for (int j = 0; j < 7; ++j) {
    int co = slot + 4 * j;
    if (co < 27)
      om_part[(((size_t)split * NB + b) * 27 + co) * HW + h * 64 + w] = acc[j];
  }
}

// ---------------- sampling metadata
__global__ __launch_bounds__(256) void k_prep_md(
    const float* __restrict__ om_part, const float* __restrict__ b_off,
    float4* __restrict__ md_w, int4* __restrict__ md_i)
{
  int t = blockIdx.x * 256 + threadIdx.x;
  if (t >= NB * 9 * HW) return;
  int hw = t & 4095;
  int bk = t >> 12;
  int k = bk % 9;
  int b = bk / 9;
  int h = hw >> 6, w = hw & 63;

  float dy = b_off[2 * k], dx = b_off[2 * k + 1], mr = b_off[18 + k];
#pragma unroll
  for (int s = 0; s < OCSPLIT; ++s) {
    size_t o = ((size_t)s * NB + b) * 27 * HW + hw;
    dy += om_part[o + (size_t)(2 * k) * HW];
    dx += om_part[o + (size_t)(2 * k + 1) * HW];
    mr += om_part[o + (size_t)(18 + k) * HW];
  }
  float m = 1.0f / (1.0f + expf(-mr));

  int ky = k / 3 - 1, kx = k % 3 - 1;
  float py = dy + (float)h + (float)ky;
  float px = dx + (float)w + (float)kx;
  float y0f = floorf(py), x0f = floorf(px);
  float fy = py - y0f, fx = px - x0f;
  int y0 = (int)y0f, x0 = (int)x0f;
  int y1 = y0 + 1, x1 = x0 + 1;

  bool vy0 = (y0 >= 0) & (y0 < 64), vy1 = (y1 >= 0) & (y1 < 64);
  bool vx0 = (x0 >= 0) & (x0 < 64), vx1 = (x1 >= 0) & (x1 < 64);
  int cy0 = min(max(y0, 0), 63), cy1 = min(max(y1, 0), 63);
  int cx0 = min(max(x0, 0), 63), cx1 = min(max(x1, 0), 63);

  float4 wv;
  wv.x = (vy0 && vx0) ? (1.f - fy) * (1.f - fx) * m : 0.f;
  wv.y = (vy0 && vx1) ? (1.f - fy) * fx * m : 0.f;
  wv.z = (vy1 && vx0) ? fy * (1.f - fx) * m : 0.f;
  wv.w = (vy1 && vx1) ? fy * fx * m : 0.f;
  int4 iv;
  iv.x = cy0 * 64 + cx0;
  iv.y = cy0 * 64 + cx1;
  iv.z = cy1 * 64 + cx0;
  iv.w = cy1 * 64 + cx1;
  md_w[t] = wv;
  md_i[t] = iv;
}

// ---------------- DCN gather + partial einsum: scalar-path weights, 64-pos tile
// grid: CSPLIT x NB x 64 ptiles. block: 4 waves; wave wv = co [32wv,32wv+32), lane = pos.
__global__ __launch_bounds__(256, 4) void k_dcn(
    const float* __restrict__ x, const float* __restrict__ w_s,
    const float4* __restrict__ md_w, const int4* __restrict__ md_i,
    float* __restrict__ part)
{
  int blk = blockIdx.x;
  int ptile = blk & 63;
  int b = (blk >> 6) & (NB - 1);
  int s4 = blk >> 8;
  int p0 = ptile * 64;
  int c0 = s4 * CPC;
  int t = threadIdx.x;
  int lane = t & 63;
  int wv = __builtin_amdgcn_readfirstlane(t >> 6);

  __shared__ float slds[2][576];

  // metadata registers: entry e = k*64 + p ; this thread owns e = t, t+256, (t+512 if t<64)
  size_t mdbase = (size_t)b * 9 * HW;
  int kA = t >> 6, pp = t & 63;
  float4 mwA = md_w[mdbase + (size_t)kA * HW + p0 + pp];
  int4  miA = md_i[mdbase + (size_t)kA * HW + p0 + pp];
  float4 mwB = md_w[mdbase + (size_t)(kA + 4) * HW + p0 + pp];
  int4  miB = md_i[mdbase + (size_t)(kA + 4) * HW + p0 + pp];
  bool hasC = (t < 64);
  float4 mwC = make_float4(0.f, 0.f, 0.f, 0.f);
  int4  miC = make_int4(0, 0, 0, 0);
  if (hasC) {
    mwC = md_w[mdbase + (size_t)8 * HW + p0 + t];
    miC = md_i[mdbase + (size_t)8 * HW + p0 + t];
  }

  float acc[32];
#pragma unroll
  for (int j = 0; j < 32; ++j) acc[j] = 0.f;

  const float* xb = x + (size_t)b * CIN * HW;

  // prefetch gathers for channel c0
  {
    const float* xc = xb + (size_t)c0 * HW;
    float a0 = xc[miA.x], a1 = xc[miA.y], a2 = xc[miA.z], a3 = xc[miA.w];
    float b0 = xc[miB.x], b1 = xc[miB.y], b2 = xc[miB.z], b3 = xc[miB.w];
    float cc0 = 0.f, cc1 = 0.f, cc2 = 0.f, cc3 = 0.f;
    if (hasC) { cc0 = xc[miC.x]; cc1 = xc[miC.y]; cc2 = xc[miC.z]; cc3 = xc[miC.w]; }

    for (int c = 0; c < CPC; ++c) {
      float* sb = slds[c & 1];
      sb[t]       = mwA.x * a0 + mwA.y * a1 + mwA.z * a2 + mwA.w * a3;
      sb[t + 256] = mwB.x * b0 + mwB.y * b1 + mwB.z * b2 + mwB.w * b3;
      if (hasC)
        sb[t + 512] = mwC.x * cc0 + mwC.y * cc1 + mwC.z * cc2 + mwC.w * cc3;

      // prefetch next channel (hidden under barrier + FMA phase)
      int nc = (c + 1 < CPC) ? c + 1 : c;
      const float* xn = xb + (size_t)(c0 + nc) * HW;
      a0 = xn[miA.x]; a1 = xn[miA.y]; a2 = xn[miA.z]; a3 = xn[miA.w];
      b0 = xn[miB.x]; b1 = xn[miB.y]; b2 = xn[miB.z]; b3 = xn[miB.w];
      if (hasC) { cc0 = xn[miC.x]; cc1 = xn[miC.y]; cc2 = xn[miC.z]; cc3 = xn[miC.w]; }

      __syncthreads();

      float sv[9];
      const float* sbl = slds[c & 1];
#pragma unroll
      for (int k = 0; k < 9; ++k)
        sv[k] = sbl[k * 64 + lane];

      // wave-uniform weight pointer -> scalar loads; SGPR operand in FMA
      const float* wc = w_s + (size_t)((c0 + c) * 4 + wv) * 288;
#pragma unroll
      for (int co = 0; co < 32; ++co) {
#pragma unroll
        for (int k = 0; k < 9; ++k)
          acc[co] = fmaf(wc[co * 9 + k], sv[k], acc[co]);
      }
    }
  }

  // write fp32 partials (bias/relu applied in k_reduce)
  size_t obase = (((size_t)s4 * NB + b) * COUT + wv * 32) * HW + p0 + lane;
#pragma unroll
  for (int co = 0; co < 32; ++co)
    part[obase + (size_t)co * HW] = acc[co];
}

// ---------------- reduce partials + bias + relu
__global__ __launch_bounds__(256) void k_reduce(
    const float* __restrict__ part, const float* __restrict__ bias_t,
    float* __restrict__ y)
{
  const int N4 = NB * COUT * HW / 4;
  int t = blockIdx.x * 256 + threadIdx.x;
  if (t >= N4) return;
  int base = t * 4;
  int co = (base / HW) & (COUT - 1);
  float4 v = *(const float4*)&part[base];
#pragma unroll
  for (int s = 1; s < CSPLIT; ++s) {
    float4 u = *(const float4*)&part[(size_t)s * (NB * COUT * HW) + base];
    v.x += u.x; v.y += u.y; v.z += u.z; v.w += u.w;
  }
  float bv = bias_t[co];
  v.x = fmaxf(v.x + bv, 0.f);
  v.y = fmaxf(v.y + bv, 0.f);
  v.z = fmaxf(v.z + bv, 0.f);
  v.w = fmaxf(v.w + bv, 0.f);
  *(float4*)&y[base] = v;
}

// ---------------- 2x bilinear upsample, align_corners
__global__ __launch_bounds__(256) void k_up(const float* __restrict__ y, float* __restrict__ out)
{
  int t = blockIdx.x * 256 + threadIdx.x;
  if (t >= NB * COUT * 128 * 128) return;
  int j = t & 127;
  int i = (t >> 7) & 127;
  int bc = t >> 14;
  const float R = (float)(63.0 / 127.0);
  float pi = (float)i * R;
  float pj = (float)j * R;
  float i0f = floorf(pi), j0f = floorf(pj);
  int i0 = (int)i0f, j0 = (int)j0f;
  int i1 = min(i0 + 1, 63), j1 = min(j0 + 1, 63);
  float f = pi - i0f, g = pj - j0f;
  const float* yb = y + (size_t)bc * HW;
  float a  = yb[i0 * 64 + j0];
  float bb = yb[i0 * 64 + j1];
  float cc = yb[i1 * 64 + j0];
  float dd = yb[i1 * 64 + j1];
  float t0 = a * (1.f - f) + cc * f;
  float t1 = bb * (1.f - f) + dd * f;
  out[t] = t0 * (1.f - g) + t1 * g;
}

extern "C" void kernel_launch(void* const* d_in, const int* in_sizes, int n_in,
                              void* d_out, int out_size, void* d_ws, size_t ws_size,
                              hipStream_t stream)
{
  const float* x     = (const float*)d_in[0];
  const float* w_off = (const float*)d_in[1];
  const float* b_off = (const float*)d_in[2];
  const float* w_dcn = (const float*)d_in[3];
  const float* b_dcn = (const float*)d_in[4];
  const float* gamma = (const float*)d_in[5];
  const float* beta  = (const float*)d_in[6];
  const float* rmean = (const float*)d_in[7];
  const float* rvar  = (const float*)d_in[8];
  float* out = (float*)d_out;

  char* ws = (char*)d_ws;
  size_t off = 0;
  auto alloc = [&](size_t bytes) {
    void* p = ws + off;
    off = (off + bytes + 255) & ~255UL;
    return p;
  };
  float*  om_part = (float*) alloc(sizeof(float)  * OCSPLIT * NB * 27 * HW);
  float4* md_w    = (float4*)alloc(sizeof(float4) * NB * 9 * HW);
  int4*   md_i    = (int4*)  alloc(sizeof(int4)   * NB * 9 * HW);
  float*  w_s     = (float*) alloc(sizeof(float)  * CIN * 1152);
  float*  bias_t  = (float*) alloc(sizeof(float)  * COUT);
  float*  ybuf    = (float*) alloc(sizeof(float)  * NB * COUT * HW);
  float*  part    = (float*) alloc(sizeof(float)  * CSPLIT * NB * COUT * HW);
  (void)ws_size;

  k_prep_w<<<(CIN * COUT * 9 + 255) / 256, 256, 0, stream>>>(
      w_dcn, b_dcn, gamma, beta, rmean, rvar, w_s, bias_t);
  k_off_conv<<<NB * 64 * OCSPLIT, 256, 0, stream>>>(x, w_off, om_part);
  k_prep_md<<<(NB * 9 * HW + 255) / 256, 256, 0, stream>>>(om_part, b_off, md_w, md_i);
  k_dcn<<<CSPLIT * NB * 64, 256, 0, stream>>>(x, w_s, md_w, md_i, part);
  k_reduce<<<(NB * COUT * HW / 4 + 255) / 256, 256, 0, stream>>>(part, bias_t, ybuf);
  k_up<<<(NB * COUT * 128 * 128 + 255) / 256, 256, 0, stream>>>(ybuf, out);
}

// Round 8
// 299.570 us; speedup vs baseline: 1.4024x; 1.4024x over previous
//
#include <hip/hip_runtime.h>
#include <math.h>

#define CIN  256
#define COUT 128
#define HW   4096
#define NB   4
#define OCSPLIT 4
#define CSPLIT  2
#define CPC  (CIN / CSPLIT)   // 128 channels per k_dcn block
#define WSTRIDE 60            // floats per 4-co weight group; broadcast-paired b128 reads hit LDS BW floor
#define WPC (32 * WSTRIDE)    // 1920 floats staged per channel

// ---------------- weight prep: w_t[c][ (co>>2)*60 + (co&3)*12 + k ] = w_dcn[co][c][k] * bn_scale
__global__ __launch_bounds__(256) void k_prep_w(
    const float* __restrict__ w_dcn, const float* __restrict__ b_dcn,
    const float* __restrict__ gamma, const float* __restrict__ beta,
    const float* __restrict__ rmean, const float* __restrict__ rvar,
    float* __restrict__ w_t, float* __restrict__ bias_t)
{
  int t = blockIdx.x * 256 + threadIdx.x;
  if (t < COUT) {
    float sc = gamma[t] * rsqrtf(rvar[t] + 1e-5f);
    bias_t[t] = b_dcn[t] * sc + beta[t] - rmean[t] * sc;
  }
  if (t >= CIN * COUT * 9) return;
  int k = t % 9;
  int q = t / 9;
  int co = q % COUT;
  int c  = q / COUT;
  float sc = gamma[co] * rsqrtf(rvar[co] + 1e-5f);
  w_t[(size_t)c * WPC + (co >> 2) * WSTRIDE + (co & 3) * 12 + k] =
      w_dcn[((size_t)co * CIN + c) * 9 + k] * sc;
}

// ---------------- offset conv (27 ch, 3x3, pad 1), split over ci into OCSPLIT partials
__global__ __launch_bounds__(256) void k_off_conv(
    const float* __restrict__ x, const float* __restrict__ w_off,
    float* __restrict__ om_part)
{
  int blk = blockIdx.x;
  int split = blk & (OCSPLIT - 1);
  int bh = blk / OCSPLIT;
  int b = bh >> 6, h = bh & 63;
  int ci0 = split * (CIN / OCSPLIT);

  __shared__ float xs[8][3][66];
  __shared__ float wl[8][27][9];

  int t = threadIdx.x;
  int w = t & 63;
  int slot = t >> 6;

  float acc[7];
#pragma unroll
  for (int j = 0; j < 7; ++j) acc[j] = 0.f;

  const int NT = (CIN / OCSPLIT) / 8;
  for (int tile = 0; tile < NT; ++tile) {
    int cb = ci0 + tile * 8;
    __syncthreads();
    for (int j = t; j < 8 * 3 * 66; j += 256) {
      int ci = j / 198, rem = j - ci * 198;
      int r = rem / 66, wp = rem - r * 66;
      int hh = h + r - 1, ww = wp - 1;
      float v = 0.f;
      if (hh >= 0 && hh < 64 && (unsigned)ww < 64u)
        v = x[(((size_t)b * CIN + cb + ci) * 64 + hh) * 64 + ww];
      xs[ci][r][wp] = v;
    }
    for (int j = t; j < 8 * 27 * 9; j += 256) {
      int ci = j / 243, rem = j - ci * 243;
      int c2 = rem / 9, k = rem - c2 * 9;
      wl[ci][c2][k] = w_off[((size_t)c2 * CIN + cb + ci) * 9 + k];
    }
    __syncthreads();
#pragma unroll 1
    for (int ci = 0; ci < 8; ++ci) {
      float xv[3][3];
#pragma unroll
      for (int r = 0; r < 3; ++r)
#pragma unroll
        for (int d = 0; d < 3; ++d)
          xv[r][d] = xs[ci][r][w + d];
#pragma unroll
      for (int j = 0; j < 7; ++j) {
        int co = slot + 4 * j;
        if (co < 27) {
#pragma unroll
          for (int r = 0; r < 3; ++r)
#pragma unroll
            for (int d = 0; d < 3; ++d)
              acc[j] = fmaf(wl[ci][co][r * 3 + d], xv[r][d], acc[j]);
        }
      }
    }
  }
#pragma unroll
  for (int j = 0; j < 7; ++j) {
    int co = slot + 4 * j;
    if (co < 27)
      om_part[(((size_t)split * NB + b) * 27 + co) * HW + h * 64 + w] = acc[j];
  }
}

// ---------------- sampling metadata
__global__ __launch_bounds__(256) void k_prep_md(
    const float* __restrict__ om_part, const float* __restrict__ b_off,
    float4* __restrict__ md_w, int4* __restrict__ md_i)
{
  int t = blockIdx.x * 256 + threadIdx.x;
  if (t >= NB * 9 * HW) return;
  int hw = t & 4095;
  int bk = t >> 12;
  int k = bk % 9;
  int b = bk / 9;
  int h = hw >> 6, w = hw & 63;

  float dy = b_off[2 * k], dx = b_off[2 * k + 1], mr = b_off[18 + k];
#pragma unroll
  for (int s = 0; s < OCSPLIT; ++s) {
    size_t o = ((size_t)s * NB + b) * 27 * HW + hw;
    dy += om_part[o + (size_t)(2 * k) * HW];
    dx += om_part[o + (size_t)(2 * k + 1) * HW];
    mr += om_part[o + (size_t)(18 + k) * HW];
  }
  float m = 1.0f / (1.0f + expf(-mr));

  int ky = k / 3 - 1, kx = k % 3 - 1;
  float py = dy + (float)h + (float)ky;
  float px = dx + (float)w + (float)kx;
  float y0f = floorf(py), x0f = floorf(px);
  float fy = py - y0f, fx = px - x0f;
  int y0 = (int)y0f, x0 = (int)x0f;
  int y1 = y0 + 1, x1 = x0 + 1;

  bool vy0 = (y0 >= 0) & (y0 < 64), vy1 = (y1 >= 0) & (y1 < 64);
  bool vx0 = (x0 >= 0) & (x0 < 64), vx1 = (x1 >= 0) & (x1 < 64);
  int cy0 = min(max(y0, 0), 63), cy1 = min(max(y1, 0), 63);
  int cx0 = min(max(x0, 0), 63), cx1 = min(max(x1, 0), 63);

  float4 wv;
  wv.x = (vy0 && vx0) ? (1.f - fy) * (1.f - fx) * m : 0.f;
  wv.y = (vy0 && vx1) ? (1.f - fy) * fx * m : 0.f;
  wv.z = (vy1 && vx0) ? fy * (1.f - fx) * m : 0.f;
  wv.w = (vy1 && vx1) ? fy * fx * m : 0.f;
  int4 iv;
  iv.x = cy0 * 64 + cx0;
  iv.y = cy0 * 64 + cx1;
  iv.z = cy1 * 64 + cx0;
  iv.w = cy1 * 64 + cx1;
  md_w[t] = wv;
  md_i[t] = iv;
}

// ---------------- DCN gather + partial einsum
// grid: CSPLIT x NB x 128 ptiles (32 pos each). block: 256 threads.
// thread: cog = t&31 (4 co's: cog*4..+3), posg = t>>5 (4 pos: posg*4..+3). acc = 4x float4.
__global__ __launch_bounds__(256, 4) void k_dcn(
    const float* __restrict__ x, const float* __restrict__ w_t,
    const float4* __restrict__ md_w, const int4* __restrict__ md_i,
    float* __restrict__ part)
{
  int blk = blockIdx.x;
  int ptile = blk & 127;
  int b = (blk >> 7) & (NB - 1);
  int s2 = blk >> 9;
  int p0 = ptile * 32;
  int c0 = s2 * CPC;
  int t = threadIdx.x;

  __shared__ __align__(16) float wlds[2][WPC];
  __shared__ __align__(16) float slds[2][288];

  // sampling metadata: entry e = k*32 + p. thread t owns e=t; t<32 also owns e=256+t (k=8).
  size_t mdbase = (size_t)b * 9 * HW;
  int k0 = t >> 5, pp = t & 31;
  float4 mw0 = md_w[mdbase + (size_t)k0 * HW + p0 + pp];
  int4  mi0 = md_i[mdbase + (size_t)k0 * HW + p0 + pp];
  bool has2 = (t < 32);
  float4 mw1 = make_float4(0.f, 0.f, 0.f, 0.f);
  int4  mi1 = make_int4(0, 0, 0, 0);
  if (has2) {
    mw1 = md_w[mdbase + (size_t)8 * HW + p0 + t];
    mi1 = md_i[mdbase + (size_t)8 * HW + p0 + t];
  }

  int cog = t & 31;
  int posg = t >> 5;

  float4 acc[4];
#pragma unroll
  for (int j = 0; j < 4; ++j) acc[j] = make_float4(0.f, 0.f, 0.f, 0.f);

  const float* xb = x + (size_t)b * CIN * HW;

  // prefetch channel c0: weights + gather taps
  const float4* wsrc = (const float4*)(w_t + (size_t)c0 * WPC);
  float4 wn0 = wsrc[t];
  float4 wn1 = (t < WPC / 4 - 256) ? wsrc[256 + t] : make_float4(0.f, 0.f, 0.f, 0.f);
  {
    const float* xc = xb + (size_t)c0 * HW;
    float a0 = xc[mi0.x], a1 = xc[mi0.y], a2 = xc[mi0.z], a3 = xc[mi0.w];
    float e0 = 0.f, e1 = 0.f, e2 = 0.f, e3 = 0.f;
    if (has2) { e0 = xc[mi1.x]; e1 = xc[mi1.y]; e2 = xc[mi1.z]; e3 = xc[mi1.w]; }

    for (int c = 0; c < CPC; ++c) {
      int p = c & 1;
      // stage from prefetch registers
      ((float4*)wlds[p])[t] = wn0;
      if (t < WPC / 4 - 256) ((float4*)wlds[p])[256 + t] = wn1;
      slds[p][t] = mw0.x * a0 + mw0.y * a1 + mw0.z * a2 + mw0.w * a3;
      if (has2)
        slds[p][256 + t] = mw1.x * e0 + mw1.y * e1 + mw1.z * e2 + mw1.w * e3;

      // prefetch channel c+1 (hidden under barrier + FMA phase)
      int nc = (c + 1 < CPC) ? c + 1 : c;
      const float4* wn = (const float4*)(w_t + (size_t)(c0 + nc) * WPC);
      wn0 = wn[t];
      if (t < WPC / 4 - 256) wn1 = wn[256 + t];
      const float* xn = xb + (size_t)(c0 + nc) * HW;
      a0 = xn[mi0.x]; a1 = xn[mi0.y]; a2 = xn[mi0.z]; a3 = xn[mi0.w];
      if (has2) { e0 = xn[mi1.x]; e1 = xn[mi1.y]; e2 = xn[mi1.z]; e3 = xn[mi1.w]; }

      __syncthreads();

      float4 sv[9];
#pragma unroll
      for (int k = 0; k < 9; ++k)
        sv[k] = *(const float4*)&slds[p][k * 32 + posg * 4];

#pragma unroll
      for (int co = 0; co < 4; ++co) {
        const float* wp = &wlds[p][cog * WSTRIDE + co * 12];
        float4 wa = *(const float4*)(wp);
        float4 wb = *(const float4*)(wp + 4);
        float w8 = wp[8];
#define FMA4(W, K) \
        acc[co].x = fmaf(W, sv[K].x, acc[co].x); \
        acc[co].y = fmaf(W, sv[K].y, acc[co].y); \
        acc[co].z = fmaf(W, sv[K].z, acc[co].z); \
        acc[co].w = fmaf(W, sv[K].w, acc[co].w);
        FMA4(wa.x, 0) FMA4(wa.y, 1) FMA4(wa.z, 2) FMA4(wa.w, 3)
        FMA4(wb.x, 4) FMA4(wb.y, 5) FMA4(wb.z, 6) FMA4(wb.w, 7)
        FMA4(w8, 8)
#undef FMA4
      }
    }
  }

  // write fp32 partials (bias/relu applied in k_reduce)
#pragma unroll
  for (int co = 0; co < 4; ++co) {
    int coa = cog * 4 + co;
    *(float4*)&part[(((size_t)s2 * NB + b) * COUT + coa) * HW + p0 + posg * 4] = acc[co];
  }
}

// ---------------- reduce partials + bias + relu
__global__ __launch_bounds__(256) void k_reduce(
    const float* __restrict__ part, const float* __restrict__ bias_t,
    float* __restrict__ y)
{
  const int N4 = NB * COUT * HW / 4;
  int t = blockIdx.x * 256 + threadIdx.x;
  if (t >= N4) return;
  int base = t * 4;
  int co = (base / HW) & (COUT - 1);
  float4 v = *(const float4*)&part[base];
#pragma unroll
  for (int s = 1; s < CSPLIT; ++s) {
    float4 u = *(const float4*)&part[(size_t)s * (NB * COUT * HW) + base];
    v.x += u.x; v.y += u.y; v.z += u.z; v.w += u.w;
  }
  float bv = bias_t[co];
  v.x = fmaxf(v.x + bv, 0.f);
  v.y = fmaxf(v.y + bv, 0.f);
  v.z = fmaxf(v.z + bv, 0.f);
  v.w = fmaxf(v.w + bv, 0.f);
  *(float4*)&y[base] = v;
}

// ---------------- 2x bilinear upsample, align_corners
__global__ __launch_bounds__(256) void k_up(const float* __restrict__ y, float* __restrict__ out)
{
  int t = blockIdx.x * 256 + threadIdx.x;
  if (t >= NB * COUT * 128 * 128) return;
  int j = t & 127;
  int i = (t >> 7) & 127;
  int bc = t >> 14;
  const float R = (float)(63.0 / 127.0);
  float pi = (float)i * R;
  float pj = (float)j * R;
  float i0f = floorf(pi), j0f = floorf(pj);
  int i0 = (int)i0f, j0 = (int)j0f;
  int i1 = min(i0 + 1, 63), j1 = min(j0 + 1, 63);
  float f = pi - i0f, g = pj - j0f;
  const float* yb = y + (size_t)bc * HW;
  float a  = yb[i0 * 64 + j0];
  float bb = yb[i0 * 64 + j1];
  float cc = yb[i1 * 64 + j0];
  float dd = yb[i1 * 64 + j1];
  float t0 = a * (1.f - f) + cc * f;
  float t1 = bb * (1.f - f) + dd * f;
  out[t] = t0 * (1.f - g) + t1 * g;
}

extern "C" void kernel_launch(void* const* d_in, const int* in_sizes, int n_in,
                              void* d_out, int out_size, void* d_ws, size_t ws_size,
                              hipStream_t stream)
{
  const float* x     = (const float*)d_in[0];
  const float* w_off = (const float*)d_in[1];
  const float* b_off = (const float*)d_in[2];
  const float* w_dcn = (const float*)d_in[3];
  const float* b_dcn = (const float*)d_in[4];
  const float* gamma = (const float*)d_in[5];
  const float* beta  = (const float*)d_in[6];
  const float* rmean = (const float*)d_in[7];
  const float* rvar  = (const float*)d_in[8];
  float* out = (float*)d_out;

  char* ws = (char*)d_ws;
  size_t off = 0;
  auto alloc = [&](size_t bytes) {
    void* p = ws + off;
    off = (off + bytes + 255) & ~255UL;
    return p;
  };
  float*  om_part = (float*) alloc(sizeof(float)  * OCSPLIT * NB * 27 * HW);
  float4* md_w    = (float4*)alloc(sizeof(float4) * NB * 9 * HW);
  int4*   md_i    = (int4*)  alloc(sizeof(int4)   * NB * 9 * HW);
  float*  w_t     = (float*) alloc(sizeof(float)  * CIN * WPC);
  float*  bias_t  = (float*) alloc(sizeof(float)  * COUT);
  float*  ybuf    = (float*) alloc(sizeof(float)  * NB * COUT * HW);
  float*  part    = (float*) alloc(sizeof(float)  * CSPLIT * NB * COUT * HW);
  (void)ws_size;

  k_prep_w<<<(CIN * COUT * 9 + 255) / 256, 256, 0, stream>>>(
      w_dcn, b_dcn, gamma, beta, rmean, rvar, w_t, bias_t);
  k_off_conv<<<NB * 64 * OCSPLIT, 256, 0, stream>>>(x, w_off, om_part);
  k_prep_md<<<(NB * 9 * HW + 255) / 256, 256, 0, stream>>>(om_part, b_off, md_w, md_i);
  k_dcn<<<CSPLIT * NB * 128, 256, 0, stream>>>(x, w_t, md_w, md_i, part);
  k_reduce<<<(NB * COUT * HW / 4 + 255) / 256, 256, 0, stream>>>(part, bias_t, ybuf);
  k_up<<<(NB * COUT * 128 * 128 + 255) / 256, 256, 0, stream>>>(ybuf, out);
}

// Round 9
// 247.160 us; speedup vs baseline: 1.6998x; 1.2121x over previous
//
#include <hip/hip_runtime.h>
#include <math.h>

#define CIN  256
#define COUT 128
#define HW   4096
#define NB   4
#define OCSPLIT 4
#define SROW  20                 // u32 words per (k,pos) S-row (16 used + 4 pad)
#define SFLAV (9 * 32 * SROW)    // words per flavor (hi / lo)

typedef short short8v __attribute__((ext_vector_type(8)));
typedef float f32x4  __attribute__((ext_vector_type(4)));

// ---------------- weight prep: bf16 hi/lo split, fragment-ready layout
// W[k][c>>3][co][c&7], plus fused BN bias
__global__ __launch_bounds__(256) void k_prep_w(
    const float* __restrict__ w_dcn, const float* __restrict__ b_dcn,
    const float* __restrict__ gamma, const float* __restrict__ beta,
    const float* __restrict__ rmean, const float* __restrict__ rvar,
    unsigned short* __restrict__ w_hi, unsigned short* __restrict__ w_lo,
    float* __restrict__ bias_t)
{
  int t = blockIdx.x * 256 + threadIdx.x;
  if (t < COUT) {
    float sc = gamma[t] * rsqrtf(rvar[t] + 1e-5f);
    bias_t[t] = b_dcn[t] * sc + beta[t] - rmean[t] * sc;
  }
  if (t >= CIN * COUT * 9) return;
  int k = t % 9;
  int q = t / 9;
  int co = q % COUT;
  int c  = q / COUT;
  float sc = gamma[co] * rsqrtf(rvar[co] + 1e-5f);
  float w = w_dcn[((size_t)co * CIN + c) * 9 + k] * sc;
  unsigned int wb = __float_as_uint(w);
  unsigned short hi = (unsigned short)(wb >> 16);          // truncated bf16
  float lof = w - __uint_as_float(wb & 0xFFFF0000u);
  unsigned short lo = (unsigned short)(__float_as_uint(lof) >> 16);
  size_t idx = (((size_t)k * 32 + (c >> 3)) * 128 + co) * 8 + (c & 7);
  w_hi[idx] = hi;
  w_lo[idx] = lo;
}

// ---------------- offset conv (27 ch, 3x3, pad 1), split over ci into OCSPLIT partials
__global__ __launch_bounds__(256) void k_off_conv(
    const float* __restrict__ x, const float* __restrict__ w_off,
    float* __restrict__ om_part)
{
  int blk = blockIdx.x;
  int split = blk & (OCSPLIT - 1);
  int bh = blk / OCSPLIT;
  int b = bh >> 6, h = bh & 63;
  int ci0 = split * (CIN / OCSPLIT);

  __shared__ float xs[8][3][66];
  __shared__ float wl[8][27][9];

  int t = threadIdx.x;
  int w = t & 63;
  int slot = t >> 6;

  float acc[7];
#pragma unroll
  for (int j = 0; j < 7; ++j) acc[j] = 0.f;

  const int NT = (CIN / OCSPLIT) / 8;
  for (int tile = 0; tile < NT; ++tile) {
    int cb = ci0 + tile * 8;
    __syncthreads();
    for (int j = t; j < 8 * 3 * 66; j += 256) {
      int ci = j / 198, rem = j - ci * 198;
      int r = rem / 66, wp = rem - r * 66;
      int hh = h + r - 1, ww = wp - 1;
      float v = 0.f;
      if (hh >= 0 && hh < 64 && (unsigned)ww < 64u)
        v = x[(((size_t)b * CIN + cb + ci) * 64 + hh) * 64 + ww];
      xs[ci][r][wp] = v;
    }
    for (int j = t; j < 8 * 27 * 9; j += 256) {
      int ci = j / 243, rem = j - ci * 243;
      int c2 = rem / 9, k = rem - c2 * 9;
      wl[ci][c2][k] = w_off[((size_t)c2 * CIN + cb + ci) * 9 + k];
    }
    __syncthreads();
#pragma unroll 1
    for (int ci = 0; ci < 8; ++ci) {
      float xv[3][3];
#pragma unroll
      for (int r = 0; r < 3; ++r)
#pragma unroll
        for (int d = 0; d < 3; ++d)
          xv[r][d] = xs[ci][r][w + d];
#pragma unroll
      for (int j = 0; j < 7; ++j) {
        int co = slot + 4 * j;
        if (co < 27) {
#pragma unroll
          for (int r = 0; r < 3; ++r)
#pragma unroll
            for (int d = 0; d < 3; ++d)
              acc[j] = fmaf(wl[ci][co][r * 3 + d], xv[r][d], acc[j]);
        }
      }
    }
  }
#pragma unroll
  for (int j = 0; j < 7; ++j) {
    int co = slot + 4 * j;
    if (co < 27)
      om_part[(((size_t)split * NB + b) * 27 + co) * HW + h * 64 + w] = acc[j];
  }
}

// ---------------- sampling metadata
__global__ __launch_bounds__(256) void k_prep_md(
    const float* __restrict__ om_part, const float* __restrict__ b_off,
    float4* __restrict__ md_w, int4* __restrict__ md_i)
{
  int t = blockIdx.x * 256 + threadIdx.x;
  if (t >= NB * 9 * HW) return;
  int hw = t & 4095;
  int bk = t >> 12;
  int k = bk % 9;
  int b = bk / 9;
  int h = hw >> 6, w = hw & 63;

  float dy = b_off[2 * k], dx = b_off[2 * k + 1], mr = b_off[18 + k];
#pragma unroll
  for (int s = 0; s < OCSPLIT; ++s) {
    size_t o = ((size_t)s * NB + b) * 27 * HW + hw;
    dy += om_part[o + (size_t)(2 * k) * HW];
    dx += om_part[o + (size_t)(2 * k + 1) * HW];
    mr += om_part[o + (size_t)(18 + k) * HW];
  }
  float m = 1.0f / (1.0f + expf(-mr));

  int ky = k / 3 - 1, kx = k % 3 - 1;
  float py = dy + (float)h + (float)ky;
  float px = dx + (float)w + (float)kx;
  float y0f = floorf(py), x0f = floorf(px);
  float fy = py - y0f, fx = px - x0f;
  int y0 = (int)y0f, x0 = (int)x0f;
  int y1 = y0 + 1, x1 = x0 + 1;

  bool vy0 = (y0 >= 0) & (y0 < 64), vy1 = (y1 >= 0) & (y1 < 64);
  bool vx0 = (x0 >= 0) & (x0 < 64), vx1 = (x1 >= 0) & (x1 < 64);
  int cy0 = min(max(y0, 0), 63), cy1 = min(max(y1, 0), 63);
  int cx0 = min(max(x0, 0), 63), cx1 = min(max(x1, 0), 63);

  float4 wv;
  wv.x = (vy0 && vx0) ? (1.f - fy) * (1.f - fx) * m : 0.f;
  wv.y = (vy0 && vx1) ? (1.f - fy) * fx * m : 0.f;
  wv.z = (vy1 && vx0) ? fy * (1.f - fx) * m : 0.f;
  wv.w = (vy1 && vx1) ? fy * fx * m : 0.f;
  int4 iv;
  iv.x = cy0 * 64 + cx0;
  iv.y = cy0 * 64 + cx1;
  iv.z = cy1 * 64 + cx0;
  iv.w = cy1 * 64 + cx1;
  md_w[t] = wv;
  md_i[t] = iv;
}

// ---------------- fused DCN gather + bf16-split MFMA einsum + bias + relu
// grid: NB x 128 ptiles (32 pos). block: 256 thr = 4 waves; wave wv = co [32wv, 32wv+32).
// K loop: 8 macro-chunks of 32 channels; per chunk: cooperative gather->LDS (bf16 hi/lo),
// then per wave 9k x 2m x 2p x 3 MFMAs accumulating f32.
__global__ __launch_bounds__(256, 2) void k_dcn(
    const float* __restrict__ x,
    const unsigned short* __restrict__ w_hi, const unsigned short* __restrict__ w_lo,
    const float* __restrict__ bias_t,
    const float4* __restrict__ md_w, const int4* __restrict__ md_i,
    float* __restrict__ y)
{
  int blk = blockIdx.x;          // NB*128
  int ptile = blk & 127;
  int b = blk >> 7;
  int p0 = ptile * 32;
  int t = threadIdx.x;
  int lane = t & 63;
  int wv = t >> 6;

  __shared__ unsigned int sbuf[2 * SFLAV];   // hi at [0], lo at [SFLAV]

  // staging role: thread t -> (k0 = t>>5, pos = t&31); t<32 also owns k=8 at pos=t
  int k0 = t >> 5, pp = t & 31;
  size_t mdbase = (size_t)b * 9 * HW;
  float4 mw0 = md_w[mdbase + (size_t)k0 * HW + p0 + pp];
  int4  mi0 = md_i[mdbase + (size_t)k0 * HW + p0 + pp];
  bool has2 = (t < 32);
  float4 mw1 = make_float4(0.f, 0.f, 0.f, 0.f);
  int4  mi1 = make_int4(0, 0, 0, 0);
  if (has2) {
    mw1 = md_w[mdbase + (size_t)8 * HW + p0 + t];
    mi1 = md_i[mdbase + (size_t)8 * HW + p0 + t];
  }

  f32x4 acc[2][2];
#pragma unroll
  for (int m = 0; m < 2; ++m)
#pragma unroll
    for (int p = 0; p < 2; ++p)
      acc[m][p] = (f32x4){0.f, 0.f, 0.f, 0.f};

  const float* xb = x + (size_t)b * CIN * HW;
  int lrow = lane & 15, lgrp = lane >> 4;

  for (int mc = 0; mc < 8; ++mc) {
    int cbase = mc * 32;
    // ---- stage S[k][pos][c] for 32 channels, bf16 hi/lo, 1-deep load pipeline
    {
      const float* xc = xb + (size_t)cbase * HW;
      float q0 = xc[mi0.x], q1 = xc[mi0.y], q2 = xc[mi0.z], q3 = xc[mi0.w];
      float r0 = xc[HW + mi0.x], r1 = xc[HW + mi0.y], r2 = xc[HW + mi0.z], r3 = xc[HW + mi0.w];
      float u0 = 0.f, u1 = 0.f, u2 = 0.f, u3 = 0.f;
      float v0 = 0.f, v1 = 0.f, v2 = 0.f, v3 = 0.f;
      if (has2) {
        u0 = xc[mi1.x]; u1 = xc[mi1.y]; u2 = xc[mi1.z]; u3 = xc[mi1.w];
        v0 = xc[HW + mi1.x]; v1 = xc[HW + mi1.y]; v2 = xc[HW + mi1.z]; v3 = xc[HW + mi1.w];
      }
      for (int it = 0; it < 16; ++it) {
        int cn = cbase + ((it < 15) ? 2 * it + 2 : 2 * it);
        const float* xn = xb + (size_t)cn * HW;
        float n0 = xn[mi0.x], n1 = xn[mi0.y], n2 = xn[mi0.z], n3 = xn[mi0.w];
        float o0 = xn[HW + mi0.x], o1 = xn[HW + mi0.y], o2 = xn[HW + mi0.z], o3 = xn[HW + mi0.w];
        float nu0 = 0.f, nu1 = 0.f, nu2 = 0.f, nu3 = 0.f;
        float nv0 = 0.f, nv1 = 0.f, nv2 = 0.f, nv3 = 0.f;
        if (has2) {
          nu0 = xn[mi1.x]; nu1 = xn[mi1.y]; nu2 = xn[mi1.z]; nu3 = xn[mi1.w];
          nv0 = xn[HW + mi1.x]; nv1 = xn[HW + mi1.y]; nv2 = xn[HW + mi1.z]; nv3 = xn[HW + mi1.w];
        }
        // current pair -> hi/lo packed
        float s0 = mw0.x * q0 + mw0.y * q1 + mw0.z * q2 + mw0.w * q3;
        float s1 = mw0.x * r0 + mw0.y * r1 + mw0.z * r2 + mw0.w * r3;
        unsigned int a0 = __float_as_uint(s0), a1 = __float_as_uint(s1);
        unsigned int hi = (a0 >> 16) | (a1 & 0xFFFF0000u);
        float l0 = s0 - __uint_as_float(a0 & 0xFFFF0000u);
        float l1 = s1 - __uint_as_float(a1 & 0xFFFF0000u);
        unsigned int lo = (__float_as_uint(l0) >> 16) | (__float_as_uint(l1) & 0xFFFF0000u);
        int widx = k0 * (32 * SROW) + pp * SROW + it;
        sbuf[widx] = hi;
        sbuf[SFLAV + widx] = lo;
        if (has2) {
          float s2 = mw1.x * u0 + mw1.y * u1 + mw1.z * u2 + mw1.w * u3;
          float s3 = mw1.x * v0 + mw1.y * v1 + mw1.z * v2 + mw1.w * v3;
          unsigned int a2 = __float_as_uint(s2), a3 = __float_as_uint(s3);
          unsigned int hi8 = (a2 >> 16) | (a3 & 0xFFFF0000u);
          float l2 = s2 - __uint_as_float(a2 & 0xFFFF0000u);
          float l3 = s3 - __uint_as_float(a3 & 0xFFFF0000u);
          unsigned int lo8 = (__float_as_uint(l2) >> 16) | (__float_as_uint(l3) & 0xFFFF0000u);
          int w8 = 8 * (32 * SROW) + t * SROW + it;
          sbuf[w8] = hi8;
          sbuf[SFLAV + w8] = lo8;
        }
        q0 = n0; q1 = n1; q2 = n2; q3 = n3;
        r0 = o0; r1 = o1; r2 = o2; r3 = o3;
        if (has2) {
          u0 = nu0; u1 = nu1; u2 = nu2; u3 = nu3;
          v0 = nv0; v1 = nv1; v2 = nv2; v3 = nv3;
        }
      }
    }
    __syncthreads();

    // ---- MFMA phase: D[co][pos] += W_k[co][c] * S_k[c][pos], 3-term split
#pragma unroll
    for (int k = 0; k < 9; ++k) {
      const unsigned int* rb = &sbuf[k * (32 * SROW) + lrow * SROW + lgrp * 4];
      short8v bh0 = *(const short8v*)rb;
      short8v bl0 = *(const short8v*)(rb + SFLAV);
      short8v bh1 = *(const short8v*)(rb + 16 * SROW);
      short8v bl1 = *(const short8v*)(rb + 16 * SROW + SFLAV);
#pragma unroll
      for (int m = 0; m < 2; ++m) {
        size_t widx = (((size_t)k * 32 + mc * 4 + lgrp) * 128 + (wv * 32 + m * 16 + lrow)) * 8;
        short8v ah = *(const short8v*)(w_hi + widx);
        short8v al = *(const short8v*)(w_lo + widx);
        acc[m][0] = __builtin_amdgcn_mfma_f32_16x16x32_bf16(ah, bh0, acc[m][0], 0, 0, 0);
        acc[m][0] = __builtin_amdgcn_mfma_f32_16x16x32_bf16(ah, bl0, acc[m][0], 0, 0, 0);
        acc[m][0] = __builtin_amdgcn_mfma_f32_16x16x32_bf16(al, bh0, acc[m][0], 0, 0, 0);
        acc[m][1] = __builtin_amdgcn_mfma_f32_16x16x32_bf16(ah, bh1, acc[m][1], 0, 0, 0);
        acc[m][1] = __builtin_amdgcn_mfma_f32_16x16x32_bf16(ah, bl1, acc[m][1], 0, 0, 0);
        acc[m][1] = __builtin_amdgcn_mfma_f32_16x16x32_bf16(al, bh1, acc[m][1], 0, 0, 0);
      }
    }
    __syncthreads();
  }

  // ---- epilogue: bias + relu, direct y write (D: col=lane&15 -> pos, row=(lane>>4)*4+j -> co)
#pragma unroll
  for (int m = 0; m < 2; ++m)
#pragma unroll
    for (int p = 0; p < 2; ++p)
#pragma unroll
      for (int j = 0; j < 4; ++j) {
        int co = wv * 32 + m * 16 + lgrp * 4 + j;
        int pos = p0 + p * 16 + lrow;
        float val = acc[m][p][j] + bias_t[co];
        y[((size_t)b * COUT + co) * HW + pos] = fmaxf(val, 0.f);
      }
}

// ---------------- 2x bilinear upsample, align_corners
__global__ __launch_bounds__(256) void k_up(const float* __restrict__ y, float* __restrict__ out)
{
  int t = blockIdx.x * 256 + threadIdx.x;
  if (t >= NB * COUT * 128 * 128) return;
  int j = t & 127;
  int i = (t >> 7) & 127;
  int bc = t >> 14;
  const float R = (float)(63.0 / 127.0);
  float pi = (float)i * R;
  float pj = (float)j * R;
  float i0f = floorf(pi), j0f = floorf(pj);
  int i0 = (int)i0f, j0 = (int)j0f;
  int i1 = min(i0 + 1, 63), j1 = min(j0 + 1, 63);
  float f = pi - i0f, g = pj - j0f;
  const float* yb = y + (size_t)bc * HW;
  float a  = yb[i0 * 64 + j0];
  float bb = yb[i0 * 64 + j1];
  float cc = yb[i1 * 64 + j0];
  float dd = yb[i1 * 64 + j1];
  float t0 = a * (1.f - f) + cc * f;
  float t1 = bb * (1.f - f) + dd * f;
  out[t] = t0 * (1.f - g) + t1 * g;
}

extern "C" void kernel_launch(void* const* d_in, const int* in_sizes, int n_in,
                              void* d_out, int out_size, void* d_ws, size_t ws_size,
                              hipStream_t stream)
{
  const float* x     = (const float*)d_in[0];
  const float* w_off = (const float*)d_in[1];
  const float* b_off = (const float*)d_in[2];
  const float* w_dcn = (const float*)d_in[3];
  const float* b_dcn = (const float*)d_in[4];
  const float* gamma = (const float*)d_in[5];
  const float* beta  = (const float*)d_in[6];
  const float* rmean = (const float*)d_in[7];
  const float* rvar  = (const float*)d_in[8];
  float* out = (float*)d_out;

  char* ws = (char*)d_ws;
  size_t off = 0;
  auto alloc = [&](size_t bytes) {
    void* p = ws + off;
    off = (off + bytes + 255) & ~255UL;
    return p;
  };
  float*  om_part = (float*) alloc(sizeof(float)  * OCSPLIT * NB * 27 * HW);
  float4* md_w    = (float4*)alloc(sizeof(float4) * NB * 9 * HW);
  int4*   md_i    = (int4*)  alloc(sizeof(int4)   * NB * 9 * HW);
  unsigned short* w_hi = (unsigned short*)alloc(sizeof(unsigned short) * 9 * CIN * COUT);
  unsigned short* w_lo = (unsigned short*)alloc(sizeof(unsigned short) * 9 * CIN * COUT);
  float*  bias_t  = (float*) alloc(sizeof(float)  * COUT);
  float*  ybuf    = (float*) alloc(sizeof(float)  * NB * COUT * HW);
  (void)ws_size; (void)in_sizes; (void)n_in; (void)out_size;

  k_prep_w<<<(CIN * COUT * 9 + 255) / 256, 256, 0, stream>>>(
      w_dcn, b_dcn, gamma, beta, rmean, rvar, w_hi, w_lo, bias_t);
  k_off_conv<<<NB * 64 * OCSPLIT, 256, 0, stream>>>(x, w_off, om_part);
  k_prep_md<<<(NB * 9 * HW + 255) / 256, 256, 0, stream>>>(om_part, b_off, md_w, md_i);
  k_dcn<<<NB * 128, 256, 0, stream>>>(x, w_hi, w_lo, bias_t, md_w, md_i, ybuf);
  k_up<<<(NB * COUT * 128 * 128 + 255) / 256, 256, 0, stream>>>(ybuf, out);
}